// Round 7
// baseline (745.355 us; speedup 1.0000x reference)
//
#include <hip/hip_runtime.h>
#include <hip/hip_bf16.h>

// Problem constants
static constexpr int B_  = 16384;
static constexpr int D_  = 2048;
static constexpr int S_  = 512;
static constexpr int E_  = 8;
static constexpr int H1_ = 1024;
static constexpr int H2_ = 512;
static constexpr float EPS_ = 1e-5f;

typedef __bf16 bf16x8 __attribute__((ext_vector_type(8)));
typedef float  f32x4  __attribute__((ext_vector_type(4)));

static __device__ __forceinline__ unsigned short f2bf(float f) {
    unsigned u = __float_as_uint(f);
    unsigned r = (u + 0x7fffu + ((u >> 16) & 1u)) >> 16;   // RTNE
    return (unsigned short)r;
}

// ---------------- prepass kernels (verified R1/R2) ----------------

__global__ void cvt_bf16_kernel(const float* __restrict__ in, ushort* __restrict__ out, long n) {
    long i = ((long)blockIdx.x * blockDim.x + threadIdx.x) * 4;
    long stride = (long)gridDim.x * blockDim.x * 4;
    for (; i < n; i += stride) {
        float4 v = *(const float4*)(in + i);
        ushort4 o;
        o.x = f2bf(v.x); o.y = f2bf(v.y); o.z = f2bf(v.z); o.w = f2bf(v.w);
        *(ushort4*)(out + i) = o;
    }
}

// in: [E][R][C] f32  ->  out: [E][C][R] bf16
__global__ void transpose_cvt_kernel(const float* __restrict__ in, ushort* __restrict__ out,
                                     int R, int C) {
    __shared__ float t[64][65];
    int nbr = R >> 6, nbc = C >> 6;
    int bid = blockIdx.x;
    int e = bid / (nbr * nbc);
    int rem = bid % (nbr * nbc);
    int br = (rem / nbc) << 6, bc = (rem % nbc) << 6;
    const float* ip = in + (size_t)e * R * C;
    ushort* op = out + (size_t)e * R * C;
    int tcol = (threadIdx.x & 15) * 4;
    int trow = threadIdx.x >> 4;
#pragma unroll
    for (int p = 0; p < 4; p++) {
        int r = trow + p * 16;
        float4 v = *(const float4*)(ip + (size_t)(br + r) * C + bc + tcol);
        t[r][tcol + 0] = v.x; t[r][tcol + 1] = v.y; t[r][tcol + 2] = v.z; t[r][tcol + 3] = v.w;
    }
    __syncthreads();
#pragma unroll
    for (int p = 0; p < 4; p++) {
        int c = trow + p * 16;
        ushort4 o;
        o.x = f2bf(t[tcol + 0][c]);
        o.y = f2bf(t[tcol + 1][c]);
        o.z = f2bf(t[tcol + 2][c]);
        o.w = f2bf(t[tcol + 3][c]);
        *(ushort4*)(op + (size_t)(bc + c) * R + br + tcol) = o;
    }
}

__global__ void fold_bn_kernel(const float* __restrict__ gamma, const float* __restrict__ beta,
                               const float* __restrict__ mean, const float* __restrict__ var,
                               const float* __restrict__ bias,
                               float* __restrict__ Sv, float* __restrict__ Tv, int n) {
    int i = blockIdx.x * 256 + threadIdx.x;
    if (i < n) {
        float s = gamma[i] * rsqrtf(var[i] + EPS_);
        Sv[i] = s;
        Tv[i] = (bias[i] - mean[i]) * s + beta[i];
    }
}

__global__ void gate_kernel(const float* __restrict__ side, const float* __restrict__ Wg,
                            const float* __restrict__ bg, float* __restrict__ gate) {
    int wid = threadIdx.x >> 6, lane = threadIdx.x & 63;
    int b = blockIdx.x * 4 + wid;
    const float* sp = side + (size_t)b * S_ + lane * 8;
    float4 v0 = *(const float4*)sp;
    float4 v1 = *(const float4*)(sp + 4);
    float sv[8] = {v0.x, v0.y, v0.z, v0.w, v1.x, v1.y, v1.z, v1.w};
    float acc[E_] = {0,0,0,0,0,0,0,0};
    const float* wrow = Wg + (size_t)(lane * 8) * E_;
#pragma unroll
    for (int j = 0; j < 8; j++) {
        float4 w0 = *(const float4*)(wrow + j * E_);
        float4 w1 = *(const float4*)(wrow + j * E_ + 4);
        acc[0] += sv[j] * w0.x; acc[1] += sv[j] * w0.y;
        acc[2] += sv[j] * w0.z; acc[3] += sv[j] * w0.w;
        acc[4] += sv[j] * w1.x; acc[5] += sv[j] * w1.y;
        acc[6] += sv[j] * w1.z; acc[7] += sv[j] * w1.w;
    }
#pragma unroll
    for (int off = 32; off; off >>= 1)
#pragma unroll
        for (int e = 0; e < E_; e++) acc[e] += __shfl_xor(acc[e], off, 64);
    float m = -1e30f;
#pragma unroll
    for (int e = 0; e < E_; e++) { acc[e] += bg[e]; m = fmaxf(m, acc[e]); }
    float s = 0.f;
#pragma unroll
    for (int e = 0; e < E_; e++) { acc[e] = __expf(acc[e] - m); s += acc[e]; }
    float inv = 1.f / s;
    if (lane < E_) gate[(size_t)b * E_ + lane] = acc[lane] * inv;
}

// ---------------- shared GEMM helpers ----------------

__device__ __forceinline__ void g2lds16(const void* g, void* l) {
    __builtin_amdgcn_global_load_lds((const __attribute__((address_space(1))) unsigned int*)g,
                                     (__attribute__((address_space(3))) unsigned int*)l,
                                     16, 0, 0);
}

#define BAR()      asm volatile("s_barrier" ::: "memory")
#define WAITVM(n)  asm volatile("s_waitcnt vmcnt(" #n ")" ::: "memory")
#define MFMA(a,b,c) __builtin_amdgcn_mfma_f32_16x16x32_bf16((a),(b),(c),0,0,0)

// ---------------- GEMM1: 256x256, 1-barrier-per-K-tile, disjoint-buffer staging ----------------
// LDS map (128 KiB): B bufs at [0,65536), A bufs at [65536,131072).
// Swizzle: LDS[row][x] = global[row][x ^ ((row&7)<<4)] (pre-swizzled global src,
// re-applied on ds_read; both-sides rule #21).
//
// R7 schedule: reads of tile t come ONLY from buffer bi; staging during tile t
// writes ONLY tile t+1 into buffer bi^1 (disjoint sets -> race-free under ANY
// intra-tile wave skew; R6's failure was staging t+2 into the read buffer with
// unbounded skew). Tile boundary: vmcnt(0) (own loads landed) + s_barrier (all
// waves' loads landed) before anyone reads bi^1. All 4 STGs issue by P2 start,
// ~2 MFMA phases before the drain, vs ~900cy load latency -> drain ~free.
// ds_reads issued one phase ahead of the consuming MFMA cluster; no intra-tile
// barriers (compiler emits fine-grained lgkmcnt per consumer).

template<int EPI>
__global__ __launch_bounds__(512, 2)
void gemm8(const ushort* __restrict__ A, const ushort* __restrict__ Bt, long aBatch,
           const float* __restrict__ Sv, const float* __restrict__ Tv,
           ushort* __restrict__ hout, float* __restrict__ outp, const float* __restrict__ gate,
           int M, int N, int K, int tilesN, int tilesM)
{
    extern __shared__ char smem[];

    const int NT  = K >> 6;
    const int tpe = tilesM * tilesN;

    const int nwg = gridDim.x, per = nwg >> 3;
    const int b0  = blockIdx.x;
    const int bid = (b0 & 7) * per + (b0 >> 3);

    const int e   = bid / tpe;
    const int rem = bid % tpe;
    const int tm  = rem / tilesN, tn = rem % tilesN;

    const char* aBase = (const char*)(A + (size_t)e * aBatch + (size_t)tm * 256 * K);
    const char* bBase = (const char*)(Bt + (size_t)e * N * K + (size_t)tn * 256 * K);
    const size_t rowB = (size_t)K * 2;
    const size_t half2 = 64 * rowB;
    const size_t half1 = 128 * rowB;

    const int tid = threadIdx.x, w = tid >> 6, lane = tid & 63;
    const int wm = w >> 2, wn = w & 3;

    const int srow = tid >> 3;
    const int scol_sw = ((tid & 7) * 16) ^ ((srow & 7) << 4);
    const int ldsW = w * 1024;

    const int lr = lane & 15;
    const int cks0 = ((lane >> 4) * 16) ^ ((lane & 7) << 4);
    const int cks1 = (64 + (lane >> 4) * 16) ^ ((lane & 7) << 4);
    const char* rdA0 = smem + 65536 + (wm * 128 + lr) * 128 + cks0;   // A ks0
    const char* rdA1 = smem + 65536 + (wm * 128 + lr) * 128 + cks1;   // A ks1
    const char* rdB0 = smem + (wn * 64 + lr) * 128 + cks0;            // B ks0
    const char* rdB1 = smem + (wn * 64 + lr) * 128 + cks1;            // B ks1

#define STG(gp, ldsoff) do { \
        g2lds16((gp), smem + (ldsoff)); \
        g2lds16((gp) + half2, smem + (ldsoff) + 8192); } while (0)

    const char* ga = aBase + (size_t)srow * rowB + scol_sw;
    const char* gb = bBase + (size_t)srow * rowB + scol_sw;

    f32x4 acc[8][4] = {};
    bf16x8 aC[4], aN[4], bC[4], bN[4];

    // prologue: stage tile0 {A-lo,A-hi,B-lo,B-hi} into buffer 0; drain; refill
    STG(ga,         65536 + 0 + 0     + ldsW);
    STG(ga + half1, 65536 + 0 + 16384 + ldsW);
    STG(gb,         0     + 0 + 0     + ldsW);
    STG(gb + half1, 0     + 0 + 16384 + ldsW);
    WAITVM(0);
    BAR();

    // initial fragment set: A mf0-3 ks0, B ks0 (buffer 0)
#pragma unroll
    for (int mf = 0; mf < 4; ++mf) aC[mf] = *(const bf16x8*)(rdA0 + mf * 2048);
#pragma unroll
    for (int nf = 0; nf < 4; ++nf) bC[nf] = *(const bf16x8*)(rdB0 + nf * 2048);

    // staging pointers for tile t+1 (advance 128 B per tile)
    const char* spA0 = ga + 128;
    const char* spA1 = ga + half1 + 128;
    const char* spB0 = gb + 128;
    const char* spB1 = gb + half1 + 128;

#pragma unroll 2
    for (int t = 0; t < NT; ++t) {
        const int bi   = t & 1;
        const int oR   = bi * 32768;            // read offset (region base in rd*)
        const int oRN  = (bi ^ 1) * 32768;      // next-tile read offset
        const int oSA  = 65536 + (bi ^ 1) * 32768;  // stage A -> next buffer
        const int oSB  = (bi ^ 1) * 32768;          // stage B -> next buffer
        const bool more = (t < NT - 1);

        // ---- P0: prefetch A ks0 hi; stage (t+1,A-lo),(t+1,A-hi); MFMA aC(ks0,lo) x bC
#pragma unroll
        for (int mf = 0; mf < 4; ++mf) aN[mf] = *(const bf16x8*)(rdA0 + oR + (4 + mf) * 2048);
        if (more) {
            STG(spA0, oSA + 0 + ldsW);
            STG(spA1, oSA + 16384 + ldsW);
        }
        __builtin_amdgcn_s_setprio(1);
#pragma unroll
        for (int mf = 0; mf < 4; ++mf)
#pragma unroll
            for (int nf = 0; nf < 4; ++nf)
                acc[mf][nf] = MFMA(aC[mf], bC[nf], acc[mf][nf]);
        __builtin_amdgcn_s_setprio(0);

        // ---- P1: prefetch A ks1 lo + B ks1; stage (t+1,B-lo); MFMA aN(ks0,hi) x bC
#pragma unroll
        for (int mf = 0; mf < 4; ++mf) aC[mf] = *(const bf16x8*)(rdA1 + oR + mf * 2048);
#pragma unroll
        for (int nf = 0; nf < 4; ++nf) bN[nf] = *(const bf16x8*)(rdB1 + oR + nf * 2048);
        if (more) STG(spB0, oSB + 0 + ldsW);
        __builtin_amdgcn_s_setprio(1);
#pragma unroll
        for (int mf = 0; mf < 4; ++mf)
#pragma unroll
            for (int nf = 0; nf < 4; ++nf)
                acc[4 + mf][nf] = MFMA(aN[mf], bC[nf], acc[4 + mf][nf]);
        __builtin_amdgcn_s_setprio(0);

        // ---- P2: prefetch A ks1 hi; stage (t+1,B-hi); MFMA aC(ks1,lo) x bN
#pragma unroll
        for (int mf = 0; mf < 4; ++mf) aN[mf] = *(const bf16x8*)(rdA1 + oR + (4 + mf) * 2048);
        if (more) STG(spB1, oSB + 16384 + ldsW);
        __builtin_amdgcn_s_setprio(1);
#pragma unroll
        for (int mf = 0; mf < 4; ++mf)
#pragma unroll
            for (int nf = 0; nf < 4; ++nf)
                acc[mf][nf] = MFMA(aC[mf], bN[nf], acc[mf][nf]);
        __builtin_amdgcn_s_setprio(0);

        // ---- P3: MFMA aN(ks1,hi) x bN
        __builtin_amdgcn_s_setprio(1);
#pragma unroll
        for (int mf = 0; mf < 4; ++mf)
#pragma unroll
            for (int nf = 0; nf < 4; ++nf)
                acc[4 + mf][nf] = MFMA(aN[mf], bN[nf], acc[4 + mf][nf]);
        __builtin_amdgcn_s_setprio(0);

        // ---- tile boundary: own loads drained, then all waves' (race-free proof)
        if (more) {
            WAITVM(0);
            BAR();
            // refill P0 fragment set for tile t+1 from buffer bi^1
#pragma unroll
            for (int mf = 0; mf < 4; ++mf) aC[mf] = *(const bf16x8*)(rdA0 + oRN + mf * 2048);
#pragma unroll
            for (int nf = 0; nf < 4; ++nf) bC[nf] = *(const bf16x8*)(rdB0 + oRN + nf * 2048);
        }

        spA0 += 128; spA1 += 128; spB0 += 128; spB1 += 128;
    }

    // epilogue: C/D layout col = lane&15, row = (lane>>4)*4 + reg
    const int rbase = tm * 256 + wm * 128 + (lane >> 4) * 4;
    const int cbase = tn * 256 + wn * 64 + lr;
    if (EPI == 1) {
#pragma unroll
        for (int nf = 0; nf < 4; ++nf) {
            const int col = cbase + nf * 16;
            const float s = Sv[e * N + col];
            const float tt = Tv[e * N + col];
#pragma unroll
            for (int mf = 0; mf < 8; ++mf) {
                const int row0 = rbase + mf * 16;
                f32x4 v = acc[mf][nf];
#pragma unroll
                for (int r = 0; r < 4; ++r) {
                    float x = v[r] * s + tt;
                    x = x > 0.f ? x : 0.f;
                    hout[((size_t)e * M + row0 + r) * N + col] = f2bf(x);
                }
            }
        }
    }
#undef STG
}

// ---------------- GEMM2e: expert-loop fused output kernel (verified R5) ----------------
// out[b][n] = sum_e gate[b][e] * relu(bn2_e( h[e][b][:] @ W2T[e][n][:] ))
// BM=128, BN=256; grid = 256 blocks = 1/CU. Flat tau over (e,kt), NT=128.
// LDS 96 KiB: B bufs [0,65536), A bufs [65536,98304).

__global__ __launch_bounds__(512, 2)
void gemm2e(const ushort* __restrict__ H, const ushort* __restrict__ W2T,
            const float* __restrict__ Sv, const float* __restrict__ Tv,
            const float* __restrict__ gate, float* __restrict__ outp)
{
    extern __shared__ char smem[];

    const int b0 = blockIdx.x;
    const int bid = (b0 & 7) * 32 + (b0 >> 3);
    const int tm = bid >> 1, tn = bid & 1;

    const size_t rowB  = (size_t)H1_ * 2;
    const size_t strAE = (size_t)B_ * H1_ * 2;
    const size_t strBE = (size_t)H2_ * H1_ * 2;
    const size_t half2 = 64 * rowB;
    const size_t halfB = 128 * rowB;

    const int tid = threadIdx.x, w = tid >> 6, lane = tid & 63;
    const int wm = w >> 2, wn = w & 3;

    const int srow = tid >> 3;
    const int scol_sw = ((tid & 7) * 16) ^ ((srow & 7) << 4);
    const int ldsW = w * 1024;

    const int lr = lane & 15;
    const int cks0 = ((lane >> 4) * 16) ^ ((lane & 7) << 4);
    const int cks1 = (64 + (lane >> 4) * 16) ^ ((lane & 7) << 4);
    const char* rdA0 = smem + 65536 + (wm * 64 + lr) * 128 + cks0;
    const char* rdA1 = smem + 65536 + (wm * 64 + lr) * 128 + cks1;
    const char* rdB0 = smem + (wn * 64 + lr) * 128 + cks0;
    const char* rdB1 = smem + (wn * 64 + lr) * 128 + cks1;

    const char* ga = (const char*)H + (size_t)tm * 128 * rowB + (size_t)srow * rowB + scol_sw;
    const char* gb = (const char*)W2T + (size_t)tn * 256 * rowB + (size_t)srow * rowB + scol_sw;

#define STG2(gp, ldsoff) do { \
        g2lds16((gp), smem + (ldsoff)); \
        g2lds16((gp) + half2, smem + (ldsoff) + 8192); } while (0)

    f32x4 acc[4][4] = {};
    f32x4 oacc[4][4] = {};
    bf16x8 a0[4], a1[4], bb0[4], bb1[4];

    g2lds16(ga,               smem + 65536 + 0     + 0    + ldsW);
    g2lds16(ga + half2,       smem + 65536 + 0     + 8192 + ldsW);
    STG2(gb,                  0     + 0     + ldsW);
    STG2(gb + halfB,          0     + 16384 + ldsW);
    g2lds16(ga + 128,         smem + 65536 + 16384 + 0    + ldsW);
    g2lds16(ga + half2 + 128, smem + 65536 + 16384 + 8192 + ldsW);
    STG2(gb + 128,            32768 + 0     + ldsW);
    WAITVM(4);
    BAR();

    const int rbase = tm * 128 + wm * 64 + (lane >> 4) * 4;
    const int cbase = tn * 256 + wn * 64 + lr;

    for (int t = 0; t < 128; ++t) {
        const int bi  = t & 1;
        const int oA  = bi * 16384;
        const int oB  = bi * 32768;

        const int t1 = t + 1, t2 = t + 2;
        const char* gB1 = gb + (size_t)(t1 >> 4) * strBE + (t1 & 15) * 128;
        const char* gA2 = ga + (size_t)(t2 >> 4) * strAE + (t2 & 15) * 128;
        const char* gB2 = gb + (size_t)(t2 >> 4) * strBE + (t2 & 15) * 128;
        const int oA2 = 65536 + ((t2 & 1) * 16384);
        const int oB1x = (t1 & 1) * 32768;
        const int oB2 = (t2 & 1) * 32768;

#pragma unroll
        for (int mf = 0; mf < 4; ++mf) a0[mf] = *(const bf16x8*)(rdA0 + oA + mf * 2048);
#pragma unroll
        for (int nf = 0; nf < 4; ++nf) bb0[nf] = *(const bf16x8*)(rdB0 + oB + nf * 2048);
        if (t1 < 128) STG2(gB1 + halfB, oB1x + 16384 + ldsW);
        BAR();
        __builtin_amdgcn_s_setprio(1);
#pragma unroll
        for (int mf = 0; mf < 4; ++mf) {
            acc[mf][0] = MFMA(a0[mf], bb0[0], acc[mf][0]);
            acc[mf][1] = MFMA(a0[mf], bb0[1], acc[mf][1]);
        }
        __builtin_amdgcn_s_setprio(0);
        BAR();
#pragma unroll
        for (int mf = 0; mf < 4; ++mf) a1[mf] = *(const bf16x8*)(rdA1 + oA + mf * 2048);
        if (t2 < 128) {
            g2lds16(gA2, smem + oA2 + 0 + ldsW);
        }
        BAR();
        __builtin_amdgcn_s_setprio(1);
#pragma unroll
        for (int mf = 0; mf < 4; ++mf) {
            acc[mf][2] = MFMA(a0[mf], bb0[2], acc[mf][2]);
            acc[mf][3] = MFMA(a0[mf], bb0[3], acc[mf][3]);
        }
        __builtin_amdgcn_s_setprio(0);
        BAR();
#pragma unroll
        for (int nf = 0; nf < 4; ++nf) bb1[nf] = *(const bf16x8*)(rdB1 + oB + nf * 2048);
        if (t2 < 128) {
            g2lds16(gA2 + half2, smem + oA2 + 8192 + ldsW);
        }
        BAR();
        __builtin_amdgcn_s_setprio(1);
#pragma unroll
        for (int mf = 0; mf < 4; ++mf) {
            acc[mf][0] = MFMA(a1[mf], bb1[0], acc[mf][0]);
            acc[mf][1] = MFMA(a1[mf], bb1[1], acc[mf][1]);
        }
        __builtin_amdgcn_s_setprio(0);
        BAR();
        if (t2 < 128) STG2(gB2, oB2 + 0 + ldsW);
        BAR();
        __builtin_amdgcn_s_setprio(1);
#pragma unroll
        for (int mf = 0; mf < 4; ++mf) {
            acc[mf][2] = MFMA(a1[mf], bb1[2], acc[mf][2]);
            acc[mf][3] = MFMA(a1[mf], bb1[3], acc[mf][3]);
        }
        __builtin_amdgcn_s_setprio(0);
        if (t < 126)       { WAITVM(4); }
        else if (t == 126) { WAITVM(0); }
        BAR();

        if ((t & 15) == 15) {
            const int e = t >> 4;
            float sc[4], tc[4];
#pragma unroll
            for (int nf = 0; nf < 4; ++nf) {
                sc[nf] = Sv[e * H2_ + cbase + nf * 16];
                tc[nf] = Tv[e * H2_ + cbase + nf * 16];
            }
#pragma unroll
            for (int mf = 0; mf < 4; ++mf) {
#pragma unroll
                for (int r = 0; r < 4; ++r) {
                    const int row = rbase + mf * 16 + r;
                    const float g = gate[(size_t)row * E_ + e];
#pragma unroll
                    for (int nf = 0; nf < 4; ++nf) {
                        float x = acc[mf][nf][r] * sc[nf] + tc[nf];
                        x = x > 0.f ? x : 0.f;
                        oacc[mf][nf][r] += g * x;
                    }
                }
            }
#pragma unroll
            for (int mf = 0; mf < 4; ++mf)
#pragma unroll
                for (int nf = 0; nf < 4; ++nf)
                    acc[mf][nf] = (f32x4){0.f, 0.f, 0.f, 0.f};
        }
    }

#pragma unroll
    for (int mf = 0; mf < 4; ++mf) {
#pragma unroll
        for (int r = 0; r < 4; ++r) {
            const int row = rbase + mf * 16 + r;
#pragma unroll
            for (int nf = 0; nf < 4; ++nf)
                outp[(size_t)row * H2_ + cbase + nf * 16] = oacc[mf][nf][r];
        }
    }
#undef STG2
}

// ---------------- launch ----------------

extern "C" void kernel_launch(void* const* d_in, const int* in_sizes, int n_in,
                              void* d_out, int out_size, void* d_ws, size_t ws_size,
                              hipStream_t stream) {
    (void)in_sizes; (void)n_in; (void)out_size; (void)ws_size;

    const float* input    = (const float*)d_in[0];
    const float* sideinfo = (const float*)d_in[1];
    const float* W1   = (const float*)d_in[2];
    const float* b1   = (const float*)d_in[3];
    const float* g1   = (const float*)d_in[4];
    const float* be1  = (const float*)d_in[5];
    const float* m1   = (const float*)d_in[6];
    const float* v1   = (const float*)d_in[7];
    const float* W2   = (const float*)d_in[8];
    const float* b2   = (const float*)d_in[9];
    const float* g2   = (const float*)d_in[10];
    const float* be2  = (const float*)d_in[11];
    const float* m2   = (const float*)d_in[12];
    const float* v2   = (const float*)d_in[13];
    const float* Wg   = (const float*)d_in[14];
    const float* bg   = (const float*)d_in[15];

    char* w = (char*)d_ws;
    size_t off = 0;
    auto carve = [&](size_t bytes) {
        void* p = w + off;
        off += (bytes + 255) & ~(size_t)255;
        return p;
    };
    ushort* Abf  = (ushort*)carve((size_t)B_ * D_ * 2);
    ushort* W1T  = (ushort*)carve((size_t)E_ * H1_ * D_ * 2);
    ushort* W2T  = (ushort*)carve((size_t)E_ * H2_ * H1_ * 2);
    ushort* hbuf = (ushort*)carve((size_t)E_ * B_ * H1_ * 2);
    float*  S1   = (float*)carve((size_t)E_ * H1_ * 4);
    float*  T1   = (float*)carve((size_t)E_ * H1_ * 4);
    float*  S2   = (float*)carve((size_t)E_ * H2_ * 4);
    float*  T2   = (float*)carve((size_t)E_ * H2_ * 4);
    float*  gatep = (float*)carve((size_t)B_ * E_ * 4);

    float* outp = (float*)d_out;

    hipFuncSetAttribute(reinterpret_cast<const void*>(&gemm8<1>),
                        hipFuncAttributeMaxDynamicSharedMemorySize, 131072);
    hipFuncSetAttribute(reinterpret_cast<const void*>(&gemm2e),
                        hipFuncAttributeMaxDynamicSharedMemorySize, 98304);

    cvt_bf16_kernel<<<4096, 256, 0, stream>>>(input, Abf, (long)B_ * D_);
    transpose_cvt_kernel<<<E_ * (D_ / 64) * (H1_ / 64), 256, 0, stream>>>(W1, W1T, D_, H1_);
    transpose_cvt_kernel<<<E_ * (H1_ / 64) * (H2_ / 64), 256, 0, stream>>>(W2, W2T, H1_, H2_);
    fold_bn_kernel<<<(E_ * H1_ + 255) / 256, 256, 0, stream>>>(g1, be1, m1, v1, b1, S1, T1, E_ * H1_);
    fold_bn_kernel<<<(E_ * H2_ + 255) / 256, 256, 0, stream>>>(g2, be2, m2, v2, b2, S2, T2, E_ * H2_);
    gate_kernel<<<B_ / 4, 256, 0, stream>>>(sideinfo, Wg, bg, gatep);

    // GEMM1: [B,D] x [D,H1] per expert -> h bf16 [E][B][H1]
    gemm8<1><<<E_ * (B_ / 256) * (H1_ / 256), 512, 131072, stream>>>(
        Abf, W1T, 0L, S1, T1, hbuf, nullptr, nullptr, B_, H1_, D_, H1_ / 256, B_ / 256);

    // GEMM2e: expert-loop, gate-weighted, writes out exactly once (no atomics)
    gemm2e<<<(B_ / 128) * (H2_ / 256), 512, 98304, stream>>>(
        hbuf, W2T, S2, T2, gatep, outp);
}